// Round 3
// baseline (2648.277 us; speedup 1.0000x reference)
//
#include <hip/hip_runtime.h>
#include <hip/hip_bf16.h>
#include <math.h>

// Problem constants
#define NB   128
#define LSEQ 512
#define EE   256
#define HH2  256
#define HHH  512
#define TT   9
#define START_TAG 7
#define STOP_TAG  8
#define NEGV -10000.0f

// LSTM config: grid = 2 dirs * 4 batch-tiles * 4 unit-tiles = 32 blocks, 512 thr (8 waves)
// wave wv: gate = wv>>1 (i,f,g,o), uh = wv&1 (unit half of the block's 64 units)
// A-tile = [32 batch x 512 K] bf16, MFMA frag order: word(ks,lane) = A[b=lane&31][k=ks*16+(lane>>5)*8+e]
// LDS: xbuf[2][16 ks][64][16B] = 32KB ; hbuf[16 ks][64][16B] = 16KB ; zbuf[4][32][66] f32
#define XBUF_BYTES 32768
#define HBUF_OFF   XBUF_BYTES
#define ZBUF_OFF   (XBUF_BYTES + 16384)
#define ZROW 66
#define LDS_BYTES (ZBUF_OFF + 4 * 32 * ZROW * 4)   // 48KB + 33792 = 82944

// Workspace layout (bytes)
#define XFRAG_BYTES  ((size_t)LSEQ * 4 * 16 * 64 * 16)        // 33,554,432
#define HFRAG_BYTES  ((size_t)LSEQ * 2 * 4 * 16 * 64 * 16)    // 67,108,864
#define HPLAIN_BYTES ((size_t)LSEQ * NB * HHH * 2)            // 67,108,864 (bf16)
#define FEATS_BYTES  ((size_t)LSEQ * NB * TT * 4)             // 2,359,296
#define OFF_HFRAG  XFRAG_BYTES
#define OFF_HPLAIN (OFF_HFRAG + HFRAG_BYTES)
#define OFF_FEATS  (OFF_HPLAIN + HPLAIN_BYTES)
#define OFF_FLAGS  (OFF_FEATS + FEATS_BYTES)
#define FLAG_UINTS 128    // 8 groups * 16-uint (64B line) spacing, slot = ut (0..3)

typedef float f32x16 __attribute__((ext_vector_type(16)));
typedef short short8 __attribute__((ext_vector_type(8)));

static __device__ __forceinline__ unsigned short f2bf(float f) {
  unsigned int u = __float_as_uint(f);
  unsigned int r = (u + 0x7fffu + ((u >> 16) & 1u)) >> 16;   // RNE
  return (unsigned short)r;
}
static __device__ __forceinline__ float sigmoidf_(float x) {
  return 1.0f / (1.0f + __expf(-x));
}
static __device__ __forceinline__ float tanhf_(float x) {
  return 2.0f / (1.0f + __expf(-2.0f * x)) - 1.0f;
}

// ---------------------------------------------------------------- flags init
__global__ void init_kernel(unsigned int* flags) {
  if (threadIdx.x < FLAG_UINTS) flags[threadIdx.x] = 0u;
}

// ---------------------------------------------------------------- embed -> x_frag (fragment order, bf16)
// word id = ((t*4+bt)*16+ks)*64 + l ; holds x[b=bt*32+(l&31)][k=ks*16+(l>>5)*8 + 0..7]
__global__ void embed_kernel(const int* __restrict__ tokens,
                             const float* __restrict__ emb,
                             uint4* __restrict__ x_frag) {
  int wid = blockIdx.x * blockDim.x + threadIdx.x;
  int l  = wid & 63;
  int ks = (wid >> 6) & 15;
  int bt = (wid >> 10) & 3;
  int t  = wid >> 12;
  int b  = bt * 32 + (l & 31);
  int k  = ks * 16 + (l >> 5) * 8;
  int tok = tokens[b * LSEQ + t];
  const float* p = emb + (size_t)tok * EE + k;
  float4 v0 = *(const float4*)p;
  float4 v1 = *(const float4*)(p + 4);
  uint4 o;
  o.x = f2bf(v0.x) | ((unsigned)f2bf(v0.y) << 16);
  o.y = f2bf(v0.z) | ((unsigned)f2bf(v0.w) << 16);
  o.z = f2bf(v1.x) | ((unsigned)f2bf(v1.y) << 16);
  o.w = f2bf(v1.z) | ((unsigned)f2bf(v1.w) << 16);
  x_frag[wid] = o;
}

// ---------------------------------------------------------------- LSTM persistent MFMA kernel
__global__ __launch_bounds__(512, 2)
void lstm_kernel(const uint4* __restrict__ x_frag,
                 const float* __restrict__ Wih_f, const float* __restrict__ Whh_f,
                 const float* __restrict__ bih_f, const float* __restrict__ bhh_f,
                 const float* __restrict__ Wih_b, const float* __restrict__ Whh_b,
                 const float* __restrict__ bih_b, const float* __restrict__ bhh_b,
                 const float* __restrict__ h0, const float* __restrict__ c0,
                 uint4* __restrict__ h_frag, ushort* __restrict__ h_plain,
                 unsigned int* __restrict__ flags) {
  extern __shared__ char smem[];
  char*  abuf = smem;                           // xbuf[2] then hbuf
  float* zbuf = (float*)(smem + ZBUF_OFF);

  const int tid  = threadIdx.x;
  const int wv   = tid >> 6;      // 0..7
  const int lane = tid & 63;
  const int gate = wv >> 1;
  const int uh   = wv & 1;
  const int d  = blockIdx.x >> 4;
  const int bt = (blockIdx.x >> 2) & 3;
  const int ut = blockIdx.x & 3;           // unit tile (64 units each)
  const int grp = d * 4 + bt;

  const float* Wih = d ? Wih_b : Wih_f;
  const float* Whh = d ? Whh_b : Whh_f;
  const float* bih = d ? bih_b : bih_f;
  const float* bhh = d ? bhh_b : bhh_f;

  // ---- weights -> B-fragments in VGPRs. B col = lane&31 (row within 32), k = ks*16+(lane>>5)*8+e
  short8 w[32];
  {
    int wrow = gate * 256 + ut * 64 + uh * 32 + (lane & 31);
#pragma unroll
    for (int ks = 0; ks < 32; ++ks) {
      int k0 = ks * 16 + (lane >> 5) * 8;
      const float* src = (k0 < 256) ? (Wih + (size_t)wrow * 256 + k0)
                                    : (Whh + (size_t)wrow * 256 + (k0 - 256));
      float4 v0 = *(const float4*)src;
      float4 v1 = *(const float4*)(src + 4);
      short8 s;
      s[0] = (short)f2bf(v0.x); s[1] = (short)f2bf(v0.y);
      s[2] = (short)f2bf(v0.z); s[3] = (short)f2bf(v0.w);
      s[4] = (short)f2bf(v1.x); s[5] = (short)f2bf(v1.y);
      s[6] = (short)f2bf(v1.z); s[7] = (short)f2bf(v1.w);
      w[ks] = s;
    }
  }

  // ---- update-thread state (tid<256): ub = tid&31 (batch), un8 = tid>>5 (unit octet 0..7)
  const int ub  = tid & 31;
  const int un8 = tid >> 5;                       // valid when tid<256
  const int bg  = bt * 32 + ub;                   // global batch
  const int ug  = ut * 64 + un8 * 8;              // global unit base (8 units)
  float creg[8];
  float bias[4][8];
  if (tid < 256) {
    const float* cp = c0 + ((size_t)d * NB + bg) * HH2 + ug;
    float4 cv0 = *(const float4*)cp;
    float4 cv1 = *(const float4*)(cp + 4);
    creg[0]=cv0.x; creg[1]=cv0.y; creg[2]=cv0.z; creg[3]=cv0.w;
    creg[4]=cv1.x; creg[5]=cv1.y; creg[6]=cv1.z; creg[7]=cv1.w;
#pragma unroll
    for (int g = 0; g < 4; ++g) {
      int gr = g * 256 + ug;
      float4 a0 = *(const float4*)(bih + gr);
      float4 a1 = *(const float4*)(bih + gr + 4);
      float4 b0 = *(const float4*)(bhh + gr);
      float4 b1 = *(const float4*)(bhh + gr + 4);
      bias[g][0]=a0.x+b0.x; bias[g][1]=a0.y+b0.y; bias[g][2]=a0.z+b0.z; bias[g][3]=a0.w+b0.w;
      bias[g][4]=a1.x+b1.x; bias[g][5]=a1.y+b1.y; bias[g][6]=a1.z+b1.z; bias[g][7]=a1.w+b1.w;
    }
  }

  // ---- staging (global_load_lds dwordx4: LDS dest = uniform base + lane*16), 2 ks per wave
  auto stage_x = [&](int tsrc) {
#pragma unroll
    for (int i = 0; i < 2; ++i) {
      int ks = wv * 2 + i;
      const char* gp = (const char*)x_frag +
          ((((size_t)tsrc * 4 + bt) * 16 + ks) * 64 + lane) * 16;
      char* lp = abuf + (tsrc & 1) * 16384 + ks * 1024;
      __builtin_amdgcn_global_load_lds(
          (const __attribute__((address_space(1))) unsigned int*)gp,
          (__attribute__((address_space(3))) unsigned int*)lp, 16, 0, 0);
    }
  };
  auto stage_h = [&](int tsrc) {   // full h[tsrc] of this (d,bt): 16 ks -> hbuf
#pragma unroll
    for (int i = 0; i < 2; ++i) {
      int ks = wv * 2 + i;
      const char* gp = (const char*)h_frag +
          (((((size_t)tsrc * 2 + d) * 4 + bt) * 16 + ks) * 64 + lane) * 16;
      char* lp = abuf + HBUF_OFF + ks * 1024;
      __builtin_amdgcn_global_load_lds(
          (const __attribute__((address_space(1))) unsigned int*)gp,
          (__attribute__((address_space(3))) unsigned int*)lp, 16, 0, 0);
    }
  };

  // ---- prologue: x[0] via DMA; h0 (fp32 global) manually packed into hbuf
  stage_x(0);
#pragma unroll
  for (int w2 = 0; w2 < 2; ++w2) {
    int wid = w2 * 512 + tid;       // 0..1023
    int ks2 = wid >> 6;             // 0..15
    int l2  = wid & 63;
    int u   = ks2 * 16 + (l2 >> 5) * 8;
    int b2  = bt * 32 + (l2 & 31);
    const float* p = h0 + ((size_t)d * NB + b2) * HH2 + u;
    float4 v0 = *(const float4*)p;
    float4 v1 = *(const float4*)(p + 4);
    uint4 o;
    o.x = f2bf(v0.x) | ((unsigned)f2bf(v0.y) << 16);
    o.y = f2bf(v0.z) | ((unsigned)f2bf(v0.w) << 16);
    o.z = f2bf(v1.x) | ((unsigned)f2bf(v1.y) << 16);
    o.w = f2bf(v1.z) | ((unsigned)f2bf(v1.w) << 16);
    *(uint4*)(abuf + HBUF_OFF + ks2 * 1024 + l2 * 16) = o;
  }
  asm volatile("s_waitcnt vmcnt(0)" ::: "memory");
  __syncthreads();

  // ---- main loop
  for (int t = 0; t < LSEQ; ++t) {
    const int cur = t & 1;
    if (t + 1 < LSEQ) stage_x(t + 1);
    if (t > 0) {
      // wave 0 polls the group's 4 flags (one cache line); others wait at the barrier
      if (wv == 0) {
        const unsigned int tgt = (unsigned int)t;
        while (true) {
          unsigned int v = __hip_atomic_load(&flags[grp * 16 + (lane & 3)],
                                             __ATOMIC_RELAXED, __HIP_MEMORY_SCOPE_AGENT);
          if (__all(v >= tgt)) break;
          __builtin_amdgcn_s_sleep(1);
        }
      }
      __syncthreads();
      stage_h(t - 1);
    }

    f32x16 acc0, acc1;
#pragma unroll
    for (int i = 0; i < 16; ++i) { acc0[i] = 0.0f; acc1[i] = 0.0f; }

    // x-half MFMAs (ks 0..15) — overlaps the h DMA
#pragma unroll
    for (int ks = 0; ks < 16; ks += 2) {
      short8 a0 = *(const short8*)(abuf + cur * 16384 + ks * 1024 + lane * 16);
      short8 a1 = *(const short8*)(abuf + cur * 16384 + (ks + 1) * 1024 + lane * 16);
      asm volatile("v_mfma_f32_32x32x16_bf16 %0, %1, %2, %0"
                   : "+v"(acc0) : "v"(a0), "v"(w[ks]));
      asm volatile("v_mfma_f32_32x32x16_bf16 %0, %1, %2, %0"
                   : "+v"(acc1) : "v"(a1), "v"(w[ks + 1]));
    }
    asm volatile("s_waitcnt vmcnt(0)" ::: "memory");  // h (and x[t+1]) staged
    __syncthreads();
    // h-half MFMAs (ks 16..31)
#pragma unroll
    for (int ks = 16; ks < 32; ks += 2) {
      short8 a0 = *(const short8*)(abuf + HBUF_OFF + (ks - 16) * 1024 + lane * 16);
      short8 a1 = *(const short8*)(abuf + HBUF_OFF + (ks - 15) * 1024 + lane * 16);
      asm volatile("v_mfma_f32_32x32x16_bf16 %0, %1, %2, %0"
                   : "+v"(acc0) : "v"(a0), "v"(w[ks]));
      asm volatile("v_mfma_f32_32x32x16_bf16 %0, %1, %2, %0"
                   : "+v"(acc1) : "v"(a1), "v"(w[ks + 1]));
    }
#pragma unroll
    for (int i = 0; i < 16; ++i) acc0[i] += acc1[i];

    // D layout: col(row-in-32) = lane&31, row(batch) = (r&3)+8*(r>>2)+4*(lane>>5)
#pragma unroll
    for (int r = 0; r < 16; ++r) {
      int brow = (r & 3) + 8 * (r >> 2) + 4 * (lane >> 5);
      zbuf[(gate * 32 + brow) * ZROW + uh * 32 + (lane & 31)] = acc0[r];
    }
    __syncthreads();

    if (tid < 256) {
      float zr[4][8];
#pragma unroll
      for (int g = 0; g < 4; ++g) {
        const float* zp = zbuf + (g * 32 + ub) * ZROW + un8 * 8;
        float4 p0 = *(const float4*)zp;
        float4 p1 = *(const float4*)(zp + 4);
        zr[g][0]=p0.x; zr[g][1]=p0.y; zr[g][2]=p0.z; zr[g][3]=p0.w;
        zr[g][4]=p1.x; zr[g][5]=p1.y; zr[g][6]=p1.z; zr[g][7]=p1.w;
      }
      unsigned short hb[8];
#pragma unroll
      for (int e = 0; e < 8; ++e) {
        float ig = sigmoidf_(zr[0][e] + bias[0][e]);
        float fg = sigmoidf_(zr[1][e] + bias[1][e]);
        float gg = tanhf_   (zr[2][e] + bias[2][e]);
        float og = sigmoidf_(zr[3][e] + bias[3][e]);
        float c = fg * creg[e] + ig * gg;
        creg[e] = c;
        hb[e] = f2bf(og * tanhf_(c));
      }
      int tt = d ? (LSEQ - 1 - t) : t;
      // h_frag slot: ks = ut*4 + (un8>>1), lane = (un8&1)*32 + ub
      size_t fo = ((((size_t)tt * 2 + d) * 4 + bt) * 16 + (ut * 4 + (un8 >> 1))) * 64
                + ((un8 & 1) * 32 + ub);
      unsigned long long w0 = (unsigned long long)(hb[0] | ((unsigned)hb[1] << 16)) |
                              ((unsigned long long)(hb[2] | ((unsigned)hb[3] << 16)) << 32);
      unsigned long long w1 = (unsigned long long)(hb[4] | ((unsigned)hb[5] << 16)) |
                              ((unsigned long long)(hb[6] | ((unsigned)hb[7] << 16)) << 32);
      unsigned long long* fp = (unsigned long long*)((char*)h_frag + fo * 16);
      __hip_atomic_store(fp,     w0, __ATOMIC_RELAXED, __HIP_MEMORY_SCOPE_AGENT);
      __hip_atomic_store(fp + 1, w1, __ATOMIC_RELAXED, __HIP_MEMORY_SCOPE_AGENT);
      // h_plain [t][b][d*256+u] bf16 (for feats)
      uint4 hp;
      hp.x = hb[0] | ((unsigned)hb[1] << 16);
      hp.y = hb[2] | ((unsigned)hb[3] << 16);
      hp.z = hb[4] | ((unsigned)hb[5] << 16);
      hp.w = hb[6] | ((unsigned)hb[7] << 16);
      *(uint4*)(h_plain + (((size_t)tt * NB + bg) * HHH) + d * HH2 + ug) = hp;
      asm volatile("s_waitcnt vmcnt(0)" ::: "memory");  // my h at coherence point
    }
    __syncthreads();                                     // all 64 units stored
    if (tid == 0)
      __hip_atomic_store(&flags[grp * 16 + ut], (unsigned int)(t + 1),
                         __ATOMIC_RELAXED, __HIP_MEMORY_SCOPE_AGENT);
  }
}

// ---------------------------------------------------------------- feats: 4 waves/block, one (t,b) row per wave
__global__ __launch_bounds__(256)
void feats_kernel(const ushort* __restrict__ h_plain,
                  const float* __restrict__ W_out, const float* __restrict__ b_out,
                  float* __restrict__ feats) {
  int wv = threadIdx.x >> 6, lane = threadIdx.x & 63;
  int wid = blockIdx.x * 4 + wv;                    // t*128 + b
  const ushort* hrow = h_plain + (size_t)wid * HHH + lane * 8;
  uint4 hv = *(const uint4*)hrow;
  float hf[8];
  hf[0] = __uint_as_float(hv.x << 16); hf[1] = __uint_as_float(hv.x & 0xffff0000u);
  hf[2] = __uint_as_float(hv.y << 16); hf[3] = __uint_as_float(hv.y & 0xffff0000u);
  hf[4] = __uint_as_float(hv.z << 16); hf[5] = __uint_as_float(hv.z & 0xffff0000u);
  hf[6] = __uint_as_float(hv.w << 16); hf[7] = __uint_as_float(hv.w & 0xffff0000u);
#pragma unroll
  for (int tg = 0; tg < TT; ++tg) {
    const float* wrow = W_out + (size_t)tg * HHH + lane * 8;
    float4 w0 = *(const float4*)wrow;
    float4 w1 = *(const float4*)(wrow + 4);
    float s = hf[0]*w0.x + hf[1]*w0.y + hf[2]*w0.z + hf[3]*w0.w
            + hf[4]*w1.x + hf[5]*w1.y + hf[6]*w1.z + hf[7]*w1.w;
#pragma unroll
    for (int off = 32; off >= 1; off >>= 1) s += __shfl_xor(s, off);
    if (lane == 0) feats[(size_t)wid * TT + tg] = s + b_out[tg];
  }
}

// ---------------------------------------------------------------- viterbi: one wave per batch
__global__ __launch_bounds__(64)
void viterbi_kernel(const float* __restrict__ feats, const float* __restrict__ trans,
                    float* __restrict__ out) {
  __shared__ float tr[TT * TT];
  __shared__ float abuf2[2][16];
  __shared__ int   bptr[LSEQ][TT];
  __shared__ float finbuf[16];
  int b = blockIdx.x, lane = threadIdx.x;
  for (int i = lane; i < TT * TT; i += 64) tr[i] = trans[i];
  if (lane < 16) abuf2[0][lane] = NEGV;
  __syncthreads();
  if (lane == START_TAG) abuf2[0][lane] = 0.f;
  int cur = 0;
  for (int l = 0; l < LSEQ; ++l) {
    float feat = (lane < TT) ? feats[((size_t)l * NB + b) * TT + lane] : 0.f;
    if (lane < TT) {
      float best = -3.4e38f; int bp = 0;
#pragma unroll
      for (int p = 0; p < TT; ++p) {
        float s2 = abuf2[cur][p] + tr[lane * TT + p];
        if (s2 > best) { best = s2; bp = p; }     // first-max = jnp.argmax
      }
      abuf2[cur ^ 1][lane] = best + feat;
      bptr[l][lane] = bp;
    }
    cur ^= 1;
  }
  if (lane < 16) finbuf[lane] = -3.4e38f;
  if (lane < TT) finbuf[lane] = abuf2[cur][lane] + tr[STOP_TAG * TT + lane];
  if (lane == 0) {
    float bestv = finbuf[0]; int btag = 0;
    for (int p = 1; p < TT; ++p) if (finbuf[p] > bestv) { bestv = finbuf[p]; btag = p; }
    out[b] = bestv;
    float* pathp = out + NB + (size_t)b * LSEQ;
    int tag = btag;
    pathp[LSEQ - 1] = (float)tag;
    for (int l = LSEQ - 1; l >= 1; --l) {
      tag = bptr[l][tag];
      pathp[l - 1] = (float)tag;
    }
  }
}

// ---------------------------------------------------------------- launch
extern "C" void kernel_launch(void* const* d_in, const int* in_sizes, int n_in,
                              void* d_out, int out_size, void* d_ws, size_t ws_size,
                              hipStream_t stream) {
  const int*   tokens = (const int*)d_in[0];
  const float* emb    = (const float*)d_in[1];
  const float* Wih_f  = (const float*)d_in[2];
  const float* Whh_f  = (const float*)d_in[3];
  const float* bih_f  = (const float*)d_in[4];
  const float* bhh_f  = (const float*)d_in[5];
  const float* Wih_b  = (const float*)d_in[6];
  const float* Whh_b  = (const float*)d_in[7];
  const float* bih_b  = (const float*)d_in[8];
  const float* bhh_b  = (const float*)d_in[9];
  const float* W_out  = (const float*)d_in[10];
  const float* b_out  = (const float*)d_in[11];
  const float* trans  = (const float*)d_in[12];
  const float* h0     = (const float*)d_in[13];
  const float* c0     = (const float*)d_in[14];
  float* out = (float*)d_out;

  char* ws = (char*)d_ws;
  uint4* x_frag  = (uint4*)ws;
  uint4* h_frag  = (uint4*)(ws + OFF_HFRAG);
  ushort* h_plain = (ushort*)(ws + OFF_HPLAIN);
  float* feats   = (float*)(ws + OFF_FEATS);
  unsigned int* flags = (unsigned int*)(ws + OFF_FLAGS);

  hipFuncSetAttribute((const void*)lstm_kernel,
                      hipFuncAttributeMaxDynamicSharedMemorySize, LDS_BYTES);

  init_kernel<<<1, 128, 0, stream>>>(flags);
  embed_kernel<<<(LSEQ * 4 * 16 * 64) / 256, 256, 0, stream>>>(tokens, emb, x_frag);
  lstm_kernel<<<32, 512, LDS_BYTES, stream>>>(x_frag, Wih_f, Whh_f, bih_f, bhh_f,
                                              Wih_b, Whh_b, bih_b, bhh_b,
                                              h0, c0, h_frag, h_plain, flags);
  feats_kernel<<<(LSEQ * NB) / 4, 256, 0, stream>>>(h_plain, W_out, b_out, feats);
  viterbi_kernel<<<NB, 64, 0, stream>>>(feats, trans, out);
}